// Round 2
// baseline (1826.274 us; speedup 1.0000x reference)
//
#include <hip/hip_runtime.h>

#define NPTS 4096
#define NSAMP 1024
#define KNN_K 32
#define FDIM 64
#define EPSF 1e-5f

// ---------------------------------------------------------------------------
// K1: farthest point sampling. One block per batch. xyz staged in LDS.
// Exact f32 semantics of the reference (no FMA contraction, first-index argmax).
// Also writes per-point squared norms (needed by kNN, same rounding as ref).
// ---------------------------------------------------------------------------
__global__ __launch_bounds__(1024) void fps_kernel(const float* __restrict__ xyz,
                                                   int* __restrict__ fps_idx,
                                                   float* __restrict__ sqnorm) {
  __shared__ float sx[NPTS], sy[NPTS], sz[NPTS];
  __shared__ float rv[16];
  __shared__ int   ri[16];
  __shared__ int   sfar;
  const int b = blockIdx.x, t = threadIdx.x;
  const float* xb = xyz + (size_t)b * 3 * NPTS;
#pragma unroll
  for (int k = 0; k < 4; ++k) {
    int n = t + k * 1024;
    sx[n] = xb[n];
    sy[n] = xb[NPTS + n];
    sz[n] = xb[2 * NPTS + n];
  }
  __syncthreads();
  float dist[4];
#pragma unroll
  for (int k = 0; k < 4; ++k) {
    int n = t + k * 1024;
    float x = sx[n], y = sy[n], z = sz[n];
    sqnorm[b * NPTS + n] =
        __fadd_rn(__fadd_rn(__fmul_rn(x, x), __fmul_rn(y, y)), __fmul_rn(z, z));
    dist[k] = 1e10f;
  }
  int far = 0;
  if (t == 0) fps_idx[b * NSAMP] = 0;
  for (int it = 1; it < NSAMP; ++it) {
    float cx = sx[far], cy = sy[far], cz = sz[far];
    float bv = -1.0f;
    int bi = 0;
#pragma unroll
    for (int k = 0; k < 4; ++k) {
      int n = t + k * 1024;
      float dx = __fsub_rn(sx[n], cx);
      float dy = __fsub_rn(sy[n], cy);
      float dz = __fsub_rn(sz[n], cz);
      float dd = __fadd_rn(__fadd_rn(__fmul_rn(dx, dx), __fmul_rn(dy, dy)),
                           __fmul_rn(dz, dz));
      float nd = fminf(dist[k], dd);
      dist[k] = nd;
      if (nd > bv) { bv = nd; bi = n; }  // n ascending -> keeps lowest index on tie
    }
    // wave-level argmax (prefer lower index on equal value)
#pragma unroll
    for (int off = 32; off > 0; off >>= 1) {
      float ov = __shfl_down(bv, off);
      int   oi = __shfl_down(bi, off);
      if (ov > bv || (ov == bv && oi < bi)) { bv = ov; bi = oi; }
    }
    int w = t >> 6;
    if ((t & 63) == 0) { rv[w] = bv; ri[w] = bi; }
    __syncthreads();
    if (t < 64) {
      float v  = (t < 16) ? rv[t] : -1.0f;
      int   i2 = (t < 16) ? ri[t] : 0;
#pragma unroll
      for (int off = 8; off > 0; off >>= 1) {
        float ov = __shfl_down(v, off);
        int   oi = __shfl_down(i2, off);
        if (ov > v || (ov == v && oi < i2)) { v = ov; i2 = oi; }
      }
      if (t == 0) { sfar = i2; fps_idx[b * NSAMP + it] = i2; }
    }
    __syncthreads();
    far = sfar;
  }
}

// ---------------------------------------------------------------------------
// K2a: gather centroid features -> out1 (B,64,S) and ws new_feats (B,S,64)
// ---------------------------------------------------------------------------
__global__ __launch_bounds__(256) void gather_feats_kernel(const float* __restrict__ feats,
                                                           const int* __restrict__ fps,
                                                           float* __restrict__ out1,
                                                           float* __restrict__ nf) {
  int i = blockIdx.x * 256 + threadIdx.x;  // 8*64*1024
  int s = i & 1023, c = (i >> 10) & 63, b = i >> 16;
  int p = fps[(b << 10) + s];
  float v = feats[((size_t)(b * 64 + c)) * NPTS + p];
  out1[(b * 64 + c) * 1024 + s] = v;
  nf[(((b << 10) + s) << 6) + c] = v;
}

// ---------------------------------------------------------------------------
// K2b: gather centroid coords -> out0 (B,3,S) and ws float4 (x,y,z,|.|^2)
// ---------------------------------------------------------------------------
__global__ __launch_bounds__(256) void gather_xyz_kernel(const float* __restrict__ xyz,
                                                         const float* __restrict__ sqnorm,
                                                         const int* __restrict__ fps,
                                                         float* __restrict__ out0,
                                                         float4* __restrict__ nx4) {
  int i = blockIdx.x * 256 + threadIdx.x;  // 8192
  int b = i >> 10, s = i & 1023;
  int p = fps[i];
  const float* xb = xyz + (size_t)b * 3 * NPTS;
  float x = xb[p], y = xb[NPTS + p], z = xb[2 * NPTS + p];
  nx4[i] = make_float4(x, y, z, sqnorm[b * NPTS + p]);
  out0[(b * 3 + 0) * 1024 + s] = x;
  out0[(b * 3 + 1) * 1024 + s] = y;
  out0[(b * 3 + 2) * 1024 + s] = z;
}

// ---------------------------------------------------------------------------
// K3: exact ordered top-32 nearest neighbors per (b,s).
// One wave per row; 64 distance keys per lane in VGPRs, key = (mapped_bits<<32)|n
// so ascending-u64 order == ascending (distance, index) order (lax.top_k ties).
// Distance matches the reference einsum path: the inner dot uses an
// FMA-accumulated chain (BLAS / numpy-SIMD semantics):
//   dot = fma(z,cz, fma(y,cy, rn(x*cx)))
// then the separate numpy ops: d = rn(rn(-2*dot + src2) + dst2).
// ---------------------------------------------------------------------------
__device__ __forceinline__ unsigned long long mk_key(float xn, float yn, float zn,
                                                     float sq, float cx, float cy,
                                                     float cz, float src2, int n) {
  float dot = __fmaf_rn(zn, cz, __fmaf_rn(yn, cy, __fmul_rn(xn, cx)));
  float d = __fadd_rn(__fadd_rn(__fmul_rn(-2.0f, dot), src2), sq);
  unsigned mb = __float_as_uint(d);
  mb = (mb & 0x80000000u) ? ~mb : (mb | 0x80000000u);
  return ((unsigned long long)mb << 32) | (unsigned)n;
}

__global__ __launch_bounds__(256, 2) void knn_kernel(const float* __restrict__ xyz,
                                                     const float* __restrict__ sqnorm,
                                                     const float4* __restrict__ nx4,
                                                     int* __restrict__ knn) {
  const int lane = threadIdx.x & 63;
  const int w = threadIdx.x >> 6;
  const int row = blockIdx.x * 4 + w;  // 0..8191
  const int b = row >> 10;
  const float4 c4 = nx4[row];
  const float cx = c4.x, cy = c4.y, cz = c4.z, src2 = c4.w;
  const float4* x4 = (const float4*)(xyz + (size_t)b * 3 * NPTS);
  const float4* y4 = (const float4*)(xyz + (size_t)b * 3 * NPTS + NPTS);
  const float4* z4 = (const float4*)(xyz + (size_t)b * 3 * NPTS + 2 * NPTS);
  const float4* s4 = (const float4*)(sqnorm + (size_t)b * NPTS);
  unsigned long long key[64];
#pragma unroll
  for (int jj = 0; jj < 16; ++jj) {
    int vi = jj * 64 + lane;
    float4 xv = x4[vi], yv = y4[vi], zv = z4[vi], sv = s4[vi];
    int n0 = vi * 4;
    key[jj * 4 + 0] = mk_key(xv.x, yv.x, zv.x, sv.x, cx, cy, cz, src2, n0);
    key[jj * 4 + 1] = mk_key(xv.y, yv.y, zv.y, sv.y, cx, cy, cz, src2, n0 + 1);
    key[jj * 4 + 2] = mk_key(xv.z, yv.z, zv.z, sv.z, cx, cy, cz, src2, n0 + 2);
    key[jj * 4 + 3] = mk_key(xv.w, yv.w, zv.w, sv.w, cx, cy, cz, src2, n0 + 3);
  }
  unsigned long long last = 0ull;
  const int out_base = row * KNN_K;
#pragma unroll 1
  for (int r = 0; r < KNN_K; ++r) {
    unsigned long long cur = ~0ull;
#pragma unroll
    for (int j = 0; j < 64; ++j) {
      unsigned long long k = key[j];
      if (k > last && k < cur) cur = k;
    }
#pragma unroll
    for (int off = 32; off > 0; off >>= 1) {
      unsigned long long o = __shfl_xor(cur, off);
      cur = (o < cur) ? o : cur;
    }
    last = cur;
    if (lane == r) knn[out_base + r] = (int)(unsigned)(cur & 0xffffffffull);
  }
}

// ---------------------------------------------------------------------------
// K4: per-batch sum / sumsq of diff (f64) for std(ddof=1)
// ---------------------------------------------------------------------------
__global__ __launch_bounds__(256) void stats_kernel(const float* __restrict__ feats,
                                                    const float* __restrict__ nf,
                                                    const int* __restrict__ knn,
                                                    double* __restrict__ stats) {
  const int b = blockIdx.x >> 5;
  const int chunk = blockIdx.x & 31;
  const int base = chunk * 65536;
  double sm = 0.0, sq = 0.0;
  for (int i = 0; i < 256; ++i) {
    int e = base + i * 256 + threadIdx.x;   // e < 2097152 per batch
    int c = e >> 15;                        // 0..63
    int sk = e & 32767;
    int s = sk >> 5, j = sk & 31;
    int p = knn[((((b << 10) + s)) << 5) + j];
    float f = feats[((size_t)(b * 64 + c)) * NPTS + p];
    float m = nf[(((b << 10) + s) << 6) + c];
    double d = (double)__fsub_rn(f, m);
    sm += d;
    sq += d * d;
  }
#pragma unroll
  for (int off = 32; off > 0; off >>= 1) {
    sm += __shfl_down(sm, off);
    sq += __shfl_down(sq, off);
  }
  __shared__ double red[8];
  int w = threadIdx.x >> 6;
  if ((threadIdx.x & 63) == 0) { red[w * 2] = sm; red[w * 2 + 1] = sq; }
  __syncthreads();
  if (threadIdx.x == 0) {
    atomicAdd(&stats[b * 2 + 0], red[0] + red[2] + red[4] + red[6]);
    atomicAdd(&stats[b * 2 + 1], red[1] + red[3] + red[5] + red[7]);
  }
}

// ---------------------------------------------------------------------------
// K5: final normalized/affine output, (B,128,S,k) coalesced along (s,k)
// ---------------------------------------------------------------------------
__global__ __launch_bounds__(256) void out_kernel(const float* __restrict__ feats,
                                                  const float* __restrict__ nf,
                                                  const int* __restrict__ knn,
                                                  const double* __restrict__ stats,
                                                  const float* __restrict__ alpha,
                                                  const float* __restrict__ beta,
                                                  float* __restrict__ out2) {
  const int plane = blockIdx.x;  // b*64 + c
  const int b = plane >> 6, c = plane & 63;
  const int sk = blockIdx.y * 256 + threadIdx.x;  // 0..32767
  const int s = sk >> 5, j = sk & 31;
  const double n = 2097152.0;
  double sm = stats[b * 2], sqs = stats[b * 2 + 1];
  double var = (sqs - sm * sm / n) / (n - 1.0);
  float stdf = (float)sqrt(var);
  float denom = stdf + EPSF;
  int p = knn[((((b << 10) + s)) << 5) + j];
  float f = feats[((size_t)(b * 64 + c)) * NPTS + p];
  float m = nf[(((b << 10) + s) << 6) + c];
  float diff = __fsub_rn(f, m);
  float g = alpha[c] * (diff / denom) + beta[c];
  size_t o1 = (((size_t)(b * 128 + c) << 10) + (size_t)s) * 32 + j;
  size_t o2 = (((size_t)(b * 128 + 64 + c) << 10) + (size_t)s) * 32 + j;
  out2[o1] = g;
  out2[o2] = g - m;
}

extern "C" void kernel_launch(void* const* d_in, const int* in_sizes, int n_in,
                              void* d_out, int out_size, void* d_ws, size_t ws_size,
                              hipStream_t stream) {
  (void)in_sizes; (void)n_in; (void)out_size; (void)ws_size;
  const float* xyz   = (const float*)d_in[0];  // (8,3,4096)
  const float* feats = (const float*)d_in[1];  // (8,64,4096)
  const float* alpha = (const float*)d_in[2];  // (64)
  const float* beta  = (const float*)d_in[3];  // (64)
  float* out  = (float*)d_out;
  float* out0 = out;                  // (8,3,1024)    = 24576
  float* out1 = out + 24576;          // (8,64,1024)   = 524288
  float* out2 = out + 24576 + 524288; // (8,128,1024,32)

  char* ws = (char*)d_ws;
  int*    fps   = (int*)ws;                   // 32768 B
  float*  sqn   = (float*)(ws + 32768);       // 131072 B
  float4* nx4   = (float4*)(ws + 163840);     // 131072 B (16B aligned)
  float*  nf    = (float*)(ws + 294912);      // 2097152 B
  int*    knn   = (int*)(ws + 2392064);       // 1048576 B
  double* stats = (double*)(ws + 3440640);    // 128 B

  hipMemsetAsync(stats, 0, 128, stream);
  fps_kernel<<<8, 1024, 0, stream>>>(xyz, fps, sqn);
  gather_feats_kernel<<<2048, 256, 0, stream>>>(feats, fps, out1, nf);
  gather_xyz_kernel<<<32, 256, 0, stream>>>(xyz, sqn, fps, out0, nx4);
  knn_kernel<<<2048, 256, 0, stream>>>(xyz, sqn, nx4, knn);
  stats_kernel<<<256, 256, 0, stream>>>(feats, nf, knn, stats);
  out_kernel<<<dim3(512, 128), 256, 0, stream>>>(feats, nf, knn, stats, alpha, beta, out2);
}

// Round 3
// 950.154 us; speedup vs baseline: 1.9221x; 1.9221x over previous
//
#include <hip/hip_runtime.h>

#define NPTS 4096
#define NSAMP 1024
#define KNN_K 32
#define FDIM 64
#define EPSF 1e-5f

// ---------------------------------------------------------------------------
// K1: farthest point sampling. One block per batch, 512 threads (8 waves).
// 8 points/lane in registers; argmax via packed (dist,idx) 44-bit key with
// DPP (VALU-pipe) reductions; one barrier + one 8B LDS write per step.
// Distance math is bit-exact vs the numpy reference (no FMA contraction,
// sequential add order, first-index tie-break).
// ---------------------------------------------------------------------------
#define DPP_MAX64(CTRL)                                                          \
  {                                                                              \
    unsigned _olo = (unsigned)__builtin_amdgcn_update_dpp(0, (int)klo, CTRL,     \
                                                          0xf, 0xf, true);       \
    unsigned _ohi = (unsigned)__builtin_amdgcn_update_dpp(0, (int)khi, CTRL,     \
                                                          0xf, 0xf, true);       \
    unsigned long long _ok = ((unsigned long long)_ohi << 32) | _olo;            \
    unsigned long long _ck = ((unsigned long long)khi << 32) | klo;              \
    if (_ok > _ck) { klo = _olo; khi = _ohi; }                                   \
  }

__global__ __launch_bounds__(512) void fps_kernel(const float* __restrict__ xyz,
                                                  int* __restrict__ fps_idx,
                                                  float* __restrict__ sqnorm) {
  __shared__ float4 pts[NPTS];
  __shared__ unsigned long long skeys[2][8];
  const int b = blockIdx.x, t = threadIdx.x;
  const int lane = t & 63, w = t >> 6;
  const float* xb = xyz + (size_t)b * 3 * NPTS;
  float px[8], py[8], pz[8], dist[8];
#pragma unroll
  for (int k = 0; k < 8; ++k) {
    int p = k * 512 + t;
    float x = xb[p], y = xb[NPTS + p], z = xb[2 * NPTS + p];
    float sq = __fadd_rn(__fadd_rn(__fmul_rn(x, x), __fmul_rn(y, y)),
                         __fmul_rn(z, z));
    px[k] = x; py[k] = y; pz[k] = z; dist[k] = 1e10f;
    pts[p] = make_float4(x, y, z, sq);
    sqnorm[b * NPTS + p] = sq;
  }
  if (t == 0) fps_idx[b * NSAMP] = 0;
  __syncthreads();
  int far = 0;
  for (int it = 1; it < NSAMP; ++it) {
    float4 c = pts[far];
    float bv = -1.0f;
    int bi = 0;
#pragma unroll
    for (int k = 0; k < 8; ++k) {
      float dx = __fsub_rn(px[k], c.x);
      float dy = __fsub_rn(py[k], c.y);
      float dz = __fsub_rn(pz[k], c.z);
      float dd = __fadd_rn(__fadd_rn(__fmul_rn(dx, dx), __fmul_rn(dy, dy)),
                           __fmul_rn(dz, dz));
      float nd = fminf(dist[k], dd);
      dist[k] = nd;
      if (nd > bv) { bv = nd; bi = k * 512 + t; }  // ascending idx -> lowest on tie
    }
    // pack 44-bit key: (dist_bits << 12) | (4095 - idx); dist >= 0 so bits are
    // monotone; u64 max == (max dist, tie -> lowest index)
    unsigned bvb = __float_as_uint(bv);
    unsigned klo = (bvb << 12) | (unsigned)(4095 - bi);
    unsigned khi = bvb >> 20;
    // intra-wave max: row_shr 1,2,4,8 then row_bcast15, row_bcast31 -> lane 63
    DPP_MAX64(0x111)
    DPP_MAX64(0x112)
    DPP_MAX64(0x114)
    DPP_MAX64(0x118)
    DPP_MAX64(0x142)
    DPP_MAX64(0x143)
    if (lane == 63) skeys[it & 1][w] = ((unsigned long long)khi << 32) | klo;
    __syncthreads();
    // every wave reduces the 8 wave-winners redundantly (no 2nd barrier)
    unsigned long long kk = skeys[it & 1][lane & 7];
    klo = (unsigned)kk;
    khi = (unsigned)(kk >> 32);
    DPP_MAX64(0x111)
    DPP_MAX64(0x112)
    DPP_MAX64(0x114)
    unsigned flo = (unsigned)__builtin_amdgcn_readlane((int)klo, 7);
    far = 4095 - (int)(flo & 0xfffu);
    if (t == 0) fps_idx[b * NSAMP + it] = far;
  }
}

// ---------------------------------------------------------------------------
// K2a: gather centroid features -> out1 (B,64,S) and ws new_feats (B,S,64)
// ---------------------------------------------------------------------------
__global__ __launch_bounds__(256) void gather_feats_kernel(const float* __restrict__ feats,
                                                           const int* __restrict__ fps,
                                                           float* __restrict__ out1,
                                                           float* __restrict__ nf) {
  int i = blockIdx.x * 256 + threadIdx.x;  // 8*64*1024
  int s = i & 1023, c = (i >> 10) & 63, b = i >> 16;
  int p = fps[(b << 10) + s];
  float v = feats[((size_t)(b * 64 + c)) * NPTS + p];
  out1[(b * 64 + c) * 1024 + s] = v;
  nf[(((b << 10) + s) << 6) + c] = v;
}

// ---------------------------------------------------------------------------
// K2b: gather centroid coords -> out0 (B,3,S) and ws float4 (x,y,z,|.|^2)
// ---------------------------------------------------------------------------
__global__ __launch_bounds__(256) void gather_xyz_kernel(const float* __restrict__ xyz,
                                                         const float* __restrict__ sqnorm,
                                                         const int* __restrict__ fps,
                                                         float* __restrict__ out0,
                                                         float4* __restrict__ nx4) {
  int i = blockIdx.x * 256 + threadIdx.x;  // 8192
  int b = i >> 10, s = i & 1023;
  int p = fps[i];
  const float* xb = xyz + (size_t)b * 3 * NPTS;
  float x = xb[p], y = xb[NPTS + p], z = xb[2 * NPTS + p];
  nx4[i] = make_float4(x, y, z, sqnorm[b * NPTS + p]);
  out0[(b * 3 + 0) * 1024 + s] = x;
  out0[(b * 3 + 1) * 1024 + s] = y;
  out0[(b * 3 + 2) * 1024 + s] = z;
}

// ---------------------------------------------------------------------------
// K3: exact ordered top-32 nearest neighbors per (b,s).
// One wave per row; 64 distance keys per lane in VGPRs, key = (mapped_bits<<32)|n
// so ascending-u64 order == ascending (distance, index) order (lax.top_k ties).
// dot uses an FMA-accumulated chain (matches the reference einsum lowering).
// ---------------------------------------------------------------------------
__device__ __forceinline__ unsigned long long mk_key(float xn, float yn, float zn,
                                                     float sq, float cx, float cy,
                                                     float cz, float src2, int n) {
  float dot = __fmaf_rn(zn, cz, __fmaf_rn(yn, cy, __fmul_rn(xn, cx)));
  float d = __fadd_rn(__fadd_rn(__fmul_rn(-2.0f, dot), src2), sq);
  unsigned mb = __float_as_uint(d);
  mb = (mb & 0x80000000u) ? ~mb : (mb | 0x80000000u);
  return ((unsigned long long)mb << 32) | (unsigned)n;
}

__global__ __launch_bounds__(256, 2) void knn_kernel(const float* __restrict__ xyz,
                                                     const float* __restrict__ sqnorm,
                                                     const float4* __restrict__ nx4,
                                                     int* __restrict__ knn) {
  const int lane = threadIdx.x & 63;
  const int w = threadIdx.x >> 6;
  const int row = blockIdx.x * 4 + w;  // 0..8191
  const int b = row >> 10;
  const float4 c4 = nx4[row];
  const float cx = c4.x, cy = c4.y, cz = c4.z, src2 = c4.w;
  const float4* x4 = (const float4*)(xyz + (size_t)b * 3 * NPTS);
  const float4* y4 = (const float4*)(xyz + (size_t)b * 3 * NPTS + NPTS);
  const float4* z4 = (const float4*)(xyz + (size_t)b * 3 * NPTS + 2 * NPTS);
  const float4* s4 = (const float4*)(sqnorm + (size_t)b * NPTS);
  unsigned long long key[64];
#pragma unroll
  for (int jj = 0; jj < 16; ++jj) {
    int vi = jj * 64 + lane;
    float4 xv = x4[vi], yv = y4[vi], zv = z4[vi], sv = s4[vi];
    int n0 = vi * 4;
    key[jj * 4 + 0] = mk_key(xv.x, yv.x, zv.x, sv.x, cx, cy, cz, src2, n0);
    key[jj * 4 + 1] = mk_key(xv.y, yv.y, zv.y, sv.y, cx, cy, cz, src2, n0 + 1);
    key[jj * 4 + 2] = mk_key(xv.z, yv.z, zv.z, sv.z, cx, cy, cz, src2, n0 + 2);
    key[jj * 4 + 3] = mk_key(xv.w, yv.w, zv.w, sv.w, cx, cy, cz, src2, n0 + 3);
  }
  unsigned long long last = 0ull;
  const int out_base = row * KNN_K;
#pragma unroll 1
  for (int r = 0; r < KNN_K; ++r) {
    unsigned long long cur = ~0ull;
#pragma unroll
    for (int j = 0; j < 64; ++j) {
      unsigned long long k = key[j];
      if (k > last && k < cur) cur = k;
    }
#pragma unroll
    for (int off = 32; off > 0; off >>= 1) {
      unsigned long long o = __shfl_xor(cur, off);
      cur = (o < cur) ? o : cur;
    }
    last = cur;
    if (lane == r) knn[out_base + r] = (int)(unsigned)(cur & 0xffffffffull);
  }
}

// ---------------------------------------------------------------------------
// K4: per-batch sum / sumsq of diff (f64) for std(ddof=1)
// ---------------------------------------------------------------------------
__global__ __launch_bounds__(256) void stats_kernel(const float* __restrict__ feats,
                                                    const float* __restrict__ nf,
                                                    const int* __restrict__ knn,
                                                    double* __restrict__ stats) {
  const int b = blockIdx.x >> 5;
  const int chunk = blockIdx.x & 31;
  const int base = chunk * 65536;
  double sm = 0.0, sq = 0.0;
  for (int i = 0; i < 256; ++i) {
    int e = base + i * 256 + threadIdx.x;   // e < 2097152 per batch
    int c = e >> 15;                        // 0..63
    int sk = e & 32767;
    int s = sk >> 5, j = sk & 31;
    int p = knn[((((b << 10) + s)) << 5) + j];
    float f = feats[((size_t)(b * 64 + c)) * NPTS + p];
    float m = nf[(((b << 10) + s) << 6) + c];
    double d = (double)__fsub_rn(f, m);
    sm += d;
    sq += d * d;
  }
#pragma unroll
  for (int off = 32; off > 0; off >>= 1) {
    sm += __shfl_down(sm, off);
    sq += __shfl_down(sq, off);
  }
  __shared__ double red[8];
  int w = threadIdx.x >> 6;
  if ((threadIdx.x & 63) == 0) { red[w * 2] = sm; red[w * 2 + 1] = sq; }
  __syncthreads();
  if (threadIdx.x == 0) {
    atomicAdd(&stats[b * 2 + 0], red[0] + red[2] + red[4] + red[6]);
    atomicAdd(&stats[b * 2 + 1], red[1] + red[3] + red[5] + red[7]);
  }
}

// ---------------------------------------------------------------------------
// K5: final normalized/affine output, (B,128,S,k) coalesced along (s,k)
// ---------------------------------------------------------------------------
__global__ __launch_bounds__(256) void out_kernel(const float* __restrict__ feats,
                                                  const float* __restrict__ nf,
                                                  const int* __restrict__ knn,
                                                  const double* __restrict__ stats,
                                                  const float* __restrict__ alpha,
                                                  const float* __restrict__ beta,
                                                  float* __restrict__ out2) {
  const int plane = blockIdx.x;  // b*64 + c
  const int b = plane >> 6, c = plane & 63;
  const int sk = blockIdx.y * 256 + threadIdx.x;  // 0..32767
  const int s = sk >> 5, j = sk & 31;
  const double n = 2097152.0;
  double sm = stats[b * 2], sqs = stats[b * 2 + 1];
  double var = (sqs - sm * sm / n) / (n - 1.0);
  float stdf = (float)sqrt(var);
  float denom = stdf + EPSF;
  int p = knn[((((b << 10) + s)) << 5) + j];
  float f = feats[((size_t)(b * 64 + c)) * NPTS + p];
  float m = nf[(((b << 10) + s) << 6) + c];
  float diff = __fsub_rn(f, m);
  float g = alpha[c] * (diff / denom) + beta[c];
  size_t o1 = (((size_t)(b * 128 + c) << 10) + (size_t)s) * 32 + j;
  size_t o2 = (((size_t)(b * 128 + 64 + c) << 10) + (size_t)s) * 32 + j;
  out2[o1] = g;
  out2[o2] = g - m;
}

extern "C" void kernel_launch(void* const* d_in, const int* in_sizes, int n_in,
                              void* d_out, int out_size, void* d_ws, size_t ws_size,
                              hipStream_t stream) {
  (void)in_sizes; (void)n_in; (void)out_size; (void)ws_size;
  const float* xyz   = (const float*)d_in[0];  // (8,3,4096)
  const float* feats = (const float*)d_in[1];  // (8,64,4096)
  const float* alpha = (const float*)d_in[2];  // (64)
  const float* beta  = (const float*)d_in[3];  // (64)
  float* out  = (float*)d_out;
  float* out0 = out;                  // (8,3,1024)    = 24576
  float* out1 = out + 24576;          // (8,64,1024)   = 524288
  float* out2 = out + 24576 + 524288; // (8,128,1024,32)

  char* ws = (char*)d_ws;
  int*    fps   = (int*)ws;                   // 32768 B
  float*  sqn   = (float*)(ws + 32768);       // 131072 B
  float4* nx4   = (float4*)(ws + 163840);     // 131072 B (16B aligned)
  float*  nf    = (float*)(ws + 294912);      // 2097152 B
  int*    knn   = (int*)(ws + 2392064);       // 1048576 B
  double* stats = (double*)(ws + 3440640);    // 128 B

  hipMemsetAsync(stats, 0, 128, stream);
  fps_kernel<<<8, 512, 0, stream>>>(xyz, fps, sqn);
  gather_feats_kernel<<<2048, 256, 0, stream>>>(feats, fps, out1, nf);
  gather_xyz_kernel<<<32, 256, 0, stream>>>(xyz, sqn, fps, out0, nx4);
  knn_kernel<<<2048, 256, 0, stream>>>(xyz, sqn, nx4, knn);
  stats_kernel<<<256, 256, 0, stream>>>(feats, nf, knn, stats);
  out_kernel<<<dim3(512, 128), 256, 0, stream>>>(feats, nf, knn, stats, alpha, beta, out2);
}